// Round 11
// baseline (344.729 us; speedup 1.0000x reference)
//
#include <hip/hip_runtime.h>
#include <hip/hip_bf16.h>

typedef float  f32x4 __attribute__((ext_vector_type(4)));
typedef short  s16x8 __attribute__((ext_vector_type(8)));

#define MEMH   256        // mem_dim
#define MSGD   512        // msg_dim
#define G3     768        // 3*H
#define W_IH_ELEMS (G3*MSGD)        // 393216
#define W_HH_ELEMS (G3*MEMH)        // 196608
#define W_TOT_ELEMS (W_IH_ELEMS + W_HH_ELEMS)  // 589824
#define W_BYTES    ((size_t)W_TOT_ELEMS * 2)   // 1179648

#define BM      64        // rows per GRU block
#define NTHR    1024      // 16 waves
#define MB0_OFF 0         // msg quarter buf0: 64x128 bf16, pitch 256 B -> 16384
#define MB1_OFF 16384     // msg quarter buf1 -> 16384
#define AH_OFF  32768     // A_h: 64x256 bf16, pitch 512 B -> 32768
#define PART_OFF 65536    // part[64][16][2] f32 -> 8192
#define STAT_OFF 73728    // stat[64][2] f32 -> 512
#define LDS_BYTES 74240

static __device__ __forceinline__ short f2bf(float x) {
    __hip_bfloat16 b = __float2bfloat16(x);
    return __builtin_bit_cast(short, b);
}
static __device__ __forceinline__ float bf2f(short s) {
    unsigned int u = ((unsigned int)(unsigned short)s) << 16;
    return __builtin_bit_cast(float, u);
}
static __device__ __forceinline__ s16x8 cvt8(f32x4 a, f32x4 b) {
    s16x8 s;
    s[0]=f2bf(a[0]); s[1]=f2bf(a[1]); s[2]=f2bf(a[2]); s[3]=f2bf(a[3]);
    s[4]=f2bf(b[0]); s[5]=f2bf(b[1]); s[6]=f2bf(b[2]); s[7]=f2bf(b[3]);
    return s;
}
static __device__ __forceinline__ float sigf(float x) {
    return 1.f / (1.f + __expf(-x));
}
static __device__ __forceinline__ float tanh_fast(float x) {
    float e = __expf(-2.f * fabsf(x));
    float t = (1.f - e) / (1.f + e);
    return copysignf(t, x);
}
static __device__ __forceinline__ f32x4 ntload4(const float* p) {
    return __builtin_nontemporal_load((const f32x4*)p);
}
static __device__ __forceinline__ void ntstore4(float* p, f32x4 v) {
    __builtin_nontemporal_store(v, (f32x4*)p);
}

// ------------------------------------------------- full copy kernel (fallback)
__global__ void smu_copy_kernel(const float* __restrict__ mem,
                                const float* __restrict__ lu,
                                float* __restrict__ out_mem,
                                float* __restrict__ out_lu,
                                long n_mem4, long n_lu4) {
    long i = (long)blockIdx.x * blockDim.x + threadIdx.x;
    long stride = (long)gridDim.x * blockDim.x;
    long total = n_mem4 + n_lu4;
    for (; i < total; i += stride) {
        if (i < n_mem4) ntstore4(out_mem + i * 4, ntload4(mem + i * 4));
        else {
            long j = (i - n_mem4) * 4;
            ntstore4(out_lu + j, ntload4(lu + j));
        }
    }
}

// ---------------------------------------- bitmap-skip copy (measured ~6 TB/s)
__global__ __launch_bounds__(256)
void smu_copy_skip_kernel(const float* __restrict__ mem,
                          const float* __restrict__ lu,
                          const unsigned* __restrict__ bm,
                          float* __restrict__ out_mem,
                          float* __restrict__ out_lu,
                          long n_nodes) {
    const long nu = n_nodes * (MEMH / 4);                 // 16B units
    const long stride = (long)gridDim.x * blockDim.x;
    const long i0 = (long)blockIdx.x * blockDim.x + threadIdx.x;

    for (long i = i0; i < nu; i += stride) {
        long r = i >> 6;
        if (!((bm[r >> 5] >> (r & 31)) & 1u))
            ntstore4(out_mem + i * 4, ntload4(mem + i * 4));
    }
    for (long i = i0; i < n_nodes; i += stride) {
        if (!((bm[i >> 5] >> (i & 31)) & 1u)) {
            float v = __builtin_nontemporal_load(lu + i);
            __builtin_nontemporal_store(v, out_lu + i);
        }
    }
}

// --------------------------------------------------- weight fp32->bf16 PACKED fragment layout
// ih: frag (t in [0,48), k in [0,16)) at elem off (t*16+k)*512; within frag
// elem idx = l*8+e  ->  source row t*16+(l&15), col k*32+(l>>4)*8+e.
// hh: frag (t in [0,48), k in [0,8)) at W_IH_ELEMS + (t*8+k)*512, same inner map.
__global__ void smu_cvtw_kernel(const float* __restrict__ wih,
                                const float* __restrict__ whh,
                                short* __restrict__ o) {
    int i = blockIdx.x * blockDim.x + threadIdx.x;
    if (i >= W_TOT_ELEMS) return;
    if (i < W_IH_ELEMS) {
        int f = i >> 9, r = i & 511, l = r >> 3, e = r & 7;
        int t = f >> 4, k = f & 15;
        int row = t * 16 + (l & 15), col = k * 32 + (l >> 4) * 8 + e;
        o[i] = f2bf(wih[row * MSGD + col]);
    } else {
        int j = i - W_IH_ELEMS;
        int f = j >> 9, r = j & 511, l = r >> 3, e = r & 7;
        int t = f >> 3, k = f & 7;
        int row = t * 16 + (l & 15), col = k * 32 + (l >> 4) * 8 + e;
        o[i] = f2bf(whh[row * MEMH + col]);
    }
}

// --------------------------------------------------- bitmap clear + set
__global__ void smu_clear_kernel(unsigned* __restrict__ p, int n) {
    int i = blockIdx.x * blockDim.x + threadIdx.x;
    if (i < n) p[i] = 0u;
}
__global__ void smu_bits_kernel(const int* __restrict__ ids,
                                unsigned* __restrict__ bm, int n) {
    int i = blockIdx.x * blockDim.x + threadIdx.x;
    if (i < n) {
        int id = ids[i];
        atomicOr(&bm[id >> 5], 1u << (id & 31));
    }
}

// ------------------------------------------------------------ B-frag loader
template<bool USE_WS>
static __device__ __forceinline__ s16x8 load_b(const float* __restrict__ Wf,
                                               const short* __restrict__ Wb,
                                               int t, int k, int ldk, int nkt, int lane) {
    if constexpr (USE_WS) {
        return *(const s16x8*)(Wb + ((size_t)(t * nkt + k) << 9) + lane * 8);
    } else {
        int row = t * 16 + (lane & 15);
        int col = k * 32 + (lane >> 4) * 8;
        f32x4 x = *(const f32x4*)(Wf + (size_t)row * ldk + col);
        f32x4 y = *(const f32x4*)(Wf + (size_t)row * ldk + col + 4);
        return cvt8(x, y);
    }
}

// --------------------------------------------------------------- GRU kernel
// 1024 threads (16 waves), BM=64 rows. Wave w owns gate-tiles t = w+16g
// (g = r,z,n) -> lane column j = w*16+lr, gate math lane-local. m=4.
// Accs: rz[m][0..1] = r,z sums (both GEMMs via MFMA C-in), gin[m], ghn[m].
// msg staged in four 128-col quarters, double-buffered 2x16KB: loads for
// quarter q+2 issue at the start of quarter q (T14 async-stage); A_h gather
// issues at k=8 and lands before GEMM2. Halves weight-L2 traffic vs BM=32.
template<bool USE_WS>
__global__ __launch_bounds__(NTHR, 1)
void smu_gru_kernel(const int*   __restrict__ ids,
                    const float* __restrict__ msg,
                    const float* __restrict__ ts,
                    const float* __restrict__ memory,
                    const float* __restrict__ W_ih,
                    const float* __restrict__ W_hh,
                    const float* __restrict__ b_ih,
                    const float* __restrict__ b_hh,
                    const float* __restrict__ gamma,
                    const float* __restrict__ beta,
                    const short* __restrict__ wsw,
                    float* __restrict__ out_mem,
                    float* __restrict__ out_lu) {
    __shared__ __align__(16) unsigned char lds[LDS_BYTES];
    const int tid = threadIdx.x;
    const long base = (long)blockIdx.x * BM;

    const int lane = tid & 63;
    const int w    = tid >> 6;              // 0..15
    const int lr   = lane & 15;
    const int lq   = lane >> 4;             // 0..3
    const int lk8  = lq * 8;
    const int sw   = (lr & 7) << 4;
    const short* Wi = wsw;
    const short* Wh = wsw + W_IH_ELEMS;

    // ---- msg staging addressing: 1024 units of 8 f32 per quarter, 1/thread
    const int   srow  = tid >> 4;           // 0..63
    const int   sc8   = tid & 15;           // 0..15
    const float* msrc = msg + (base + srow) * MSGD + sc8 * 8;
    const int   mbyte = (srow * 256 + sc8 * 16) ^ ((srow & 7) << 4);

    // ---- A_h staging addressing: 2048 units, 2/thread (rows r and r+32)
    const int   hrow  = tid >> 5;           // 0..31
    const int   hc8   = tid & 31;
    const int   ahb0  = AH_OFF + ((hrow * 512 + hc8 * 16) ^ ((hrow & 7) << 4));
    const int   ahb1  = ahb0 + 32 * 512;    // (row+32)&7 == row&7

    // ---- prologue: issue q0,q1 msg loads + first B frags, then write q0,q1
    f32x4 s0a = ntload4(msrc),       s0b = ntload4(msrc + 4);
    f32x4 s1a = ntload4(msrc + 128), s1b = ntload4(msrc + 132);

    s16x8 b[2][3];
    #pragma unroll
    for (int i = 0; i < 3; ++i) b[0][i] = load_b<USE_WS>(W_ih, Wi, w + 16*i, 0, MSGD, 16, lane);
    #pragma unroll
    for (int i = 0; i < 3; ++i) b[1][i] = load_b<USE_WS>(W_ih, Wi, w + 16*i, 1, MSGD, 16, lane);

    *(s16x8*)(lds + MB0_OFF + mbyte) = cvt8(s0a, s0b);
    *(s16x8*)(lds + MB1_OFF + mbyte) = cvt8(s1a, s1b);
    __syncthreads();

    f32x4 rz[4][2] = {};    // [m][0]=r-sum [1]=z-sum (both GEMMs accumulate)
    f32x4 gin[4]   = {};    // gi_n
    f32x4 ghn[4]   = {};    // gh_n

    f32x4 s2a, s2b, s3a, s3b;
    f32x4 ah0, ah1, ah2, ah3;

    // ---- GEMM 1: K=512, 16 k-steps in 4 quarters; staging pipelined through
    #pragma unroll
    for (int k = 0; k < 16; ++k) {
        if (k == 0) { s2a = ntload4(msrc + 256); s2b = ntload4(msrc + 260); }
        if (k == 4) { s3a = ntload4(msrc + 384); s3b = ntload4(msrc + 388); }
        if (k == 8) {
            __syncthreads();   // all q0 reads (k<=3) done everywhere
            *(s16x8*)(lds + MB0_OFF + mbyte) = cvt8(s2a, s2b);
            __syncthreads();   // q2 ready
            int id0 = ids[base + hrow];
            int id1 = ids[base + hrow + 32];
            const float* h0 = memory + (size_t)id0 * MEMH + hc8 * 8;
            const float* h1 = memory + (size_t)id1 * MEMH + hc8 * 8;
            ah0 = ntload4(h0); ah1 = ntload4(h0 + 4);
            ah2 = ntload4(h1); ah3 = ntload4(h1 + 4);
        }
        if (k == 12) {
            __syncthreads();   // all q1 reads (k<=7) done
            *(s16x8*)(lds + MB1_OFF + mbyte) = cvt8(s3a, s3b);
            __syncthreads();   // q3 ready
        }
        const int mboff = (k & 4) ? MB1_OFF : MB0_OFF;
        const int cb = ((k & 3) * 32 + lk8) * 2;
        #pragma unroll
        for (int m = 0; m < 4; ++m) {
            s16x8 a = *(const s16x8*)(lds + mboff + (((m*16 + lr) * 256 + cb) ^ sw));
            rz[m][0] = __builtin_amdgcn_mfma_f32_16x16x32_bf16(a, b[k & 1][0], rz[m][0], 0, 0, 0);
            rz[m][1] = __builtin_amdgcn_mfma_f32_16x16x32_bf16(a, b[k & 1][1], rz[m][1], 0, 0, 0);
            gin[m]   = __builtin_amdgcn_mfma_f32_16x16x32_bf16(a, b[k & 1][2], gin[m],   0, 0, 0);
        }
        if (k < 14) {
            #pragma unroll
            for (int i = 0; i < 3; ++i)
                b[k & 1][i] = load_b<USE_WS>(W_ih, Wi, w + 16*i, k + 2, MSGD, 16, lane);
        }
    }

    // ---- write A_h, then GEMM 2: K=256, 8 k-steps
    __syncthreads();   // all msg-buffer reads done (AH region untouched anyway)
    *(s16x8*)(lds + ahb0) = cvt8(ah0, ah1);
    *(s16x8*)(lds + ahb1) = cvt8(ah2, ah3);
    __syncthreads();

    {
        #pragma unroll
        for (int i = 0; i < 3; ++i) b[0][i] = load_b<USE_WS>(W_hh, Wh, w + 16*i, 0, MEMH, 8, lane);
        #pragma unroll
        for (int i = 0; i < 3; ++i) b[1][i] = load_b<USE_WS>(W_hh, Wh, w + 16*i, 1, MEMH, 8, lane);
        #pragma unroll
        for (int k = 0; k < 8; ++k) {
            const int cb = (k * 32 + lk8) * 2;
            #pragma unroll
            for (int m = 0; m < 4; ++m) {
                s16x8 a = *(const s16x8*)(lds + AH_OFF + (((m*16 + lr) * 512 + cb) ^ sw));
                rz[m][0] = __builtin_amdgcn_mfma_f32_16x16x32_bf16(a, b[k & 1][0], rz[m][0], 0, 0, 0);
                rz[m][1] = __builtin_amdgcn_mfma_f32_16x16x32_bf16(a, b[k & 1][1], rz[m][1], 0, 0, 0);
                ghn[m]   = __builtin_amdgcn_mfma_f32_16x16x32_bf16(a, b[k & 1][2], ghn[m],   0, 0, 0);
            }
            if (k < 6) {
                #pragma unroll
                for (int i = 0; i < 3; ++i)
                    b[k & 1][i] = load_b<USE_WS>(W_hh, Wh, w + 16*i, k + 2, MEMH, 8, lane);
            }
        }
    }

    // ---- gate epilogue in registers (A_h LDS intact). Lane column j.
    const int j = w * 16 + lr;               // 0..255
    f32x4 o_[4];
    {
        const float br = b_ih[j]       + b_hh[j];
        const float bz = b_ih[256 + j] + b_hh[256 + j];
        const float bihn = b_ih[512 + j], bhhn = b_hh[512 + j];
        #pragma unroll
        for (int m = 0; m < 4; ++m) {
            #pragma unroll
            for (int q = 0; q < 4; ++q) {
                int row = m * 16 + lq * 4 + q;
                float r = sigf(rz[m][0][q] + br);
                float z = sigf(rz[m][1][q] + bz);
                float n = tanh_fast(gin[m][q] + bihn + r * (ghn[m][q] + bhhn));
                float hv = bf2f(*(const short*)(lds + AH_OFF + ((row * 512 + j * 2) ^ ((row & 7) << 4))));
                o_[m][q] = (1.f - z) * n + z * hv;
            }
        }
    }

    // ---- per-wave LN partials: sum over this wave's 16 cols per row
    {
        float* part = (float*)(lds + PART_OFF);
        #pragma unroll
        for (int m = 0; m < 4; ++m) {
            #pragma unroll
            for (int q = 0; q < 4; ++q) {
                float v = o_[m][q];
                float s1 = v, s2 = v * v;
                #pragma unroll
                for (int mk = 1; mk < 16; mk <<= 1) {
                    s1 += __shfl_xor(s1, mk);
                    s2 += __shfl_xor(s2, mk);
                }
                if (lr == 0) {
                    int row = m * 16 + lq * 4 + q;
                    part[(row * 16 + w) * 2]     = s1;
                    part[(row * 16 + w) * 2 + 1] = s2;
                }
            }
        }
    }
    __syncthreads();

    // ---- stage-2: wave w reduces rows 4w..4w+3 (lane group lq -> one row)
    {
        const float* part = (const float*)(lds + PART_OFF);
        int row = w * 4 + lq;
        float s1 = part[(row * 16 + lr) * 2];
        float s2 = part[(row * 16 + lr) * 2 + 1];
        #pragma unroll
        for (int mk = 1; mk < 16; mk <<= 1) {
            s1 += __shfl_xor(s1, mk);
            s2 += __shfl_xor(s2, mk);
        }
        if (lr == 0) {
            float mu  = s1 * (1.f / 256.f);
            float var = fmaxf(s2 * (1.f / 256.f) - mu * mu, 0.f);
            float* st = (float*)(lds + STAT_OFF);
            st[row * 2]     = mu;
            st[row * 2 + 1] = rsqrtf(var + 1e-5f);
        }
    }
    __syncthreads();

    // ---- normalize + scatter
    {
        const float* st = (const float*)(lds + STAT_OFF);
        const float ga = gamma[j], be = beta[j];
        #pragma unroll
        for (int m = 0; m < 4; ++m) {
            #pragma unroll
            for (int q = 0; q < 4; ++q) {
                int row = m * 16 + lq * 4 + q;
                float mu  = st[row * 2];
                float inv = st[row * 2 + 1];
                int id = ids[base + row];
                float y = (o_[m][q] - mu) * inv * ga + be;
                __builtin_nontemporal_store(y, out_mem + (size_t)id * MEMH + j);
            }
        }
        if (w == 0) {
            int id = ids[base + lane];
            __builtin_nontemporal_store(ts[base + lane], out_lu + id);
        }
    }
}

// ------------------------------------------------------------------- launcher
extern "C" void kernel_launch(void* const* d_in, const int* in_sizes, int n_in,
                              void* d_out, int out_size, void* d_ws, size_t ws_size,
                              hipStream_t stream) {
    (void)n_in; (void)out_size;
    const int*   ids = (const int*)  d_in[0];
    const float* msg = (const float*)d_in[1];
    const float* ts  = (const float*)d_in[2];
    const float* mem = (const float*)d_in[3];
    const float* lu  = (const float*)d_in[4];
    const float* Wih = (const float*)d_in[5];
    const float* Whh = (const float*)d_in[6];
    const float* bih = (const float*)d_in[7];
    const float* bhh = (const float*)d_in[8];
    const float* gam = (const float*)d_in[9];
    const float* bet = (const float*)d_in[10];

    const int  n_upd   = in_sizes[0];                 // 65536
    const long n_nodes = (long)in_sizes[3] / MEMH;    // 500000

    float* out_mem = (float*)d_out;
    float* out_lu  = out_mem + (size_t)n_nodes * MEMH;

    const int    bm_words     = (int)((n_nodes + 31) / 32) + 4;   // padded
    const size_t bm_bytes_pad = (size_t)bm_words * 4;
    const bool ws_w  = (d_ws != nullptr) && (ws_size >= W_BYTES);
    const bool ws_bm = (d_ws != nullptr) && (ws_size >= W_BYTES + bm_bytes_pad);

    short*    wsw = (short*)d_ws;
    unsigned* bm  = (unsigned*)((char*)d_ws + W_BYTES);

    const int grid = n_upd / BM;   // 65536/64 = 1024

    if (ws_bm && ws_w) {
        // clear -> bits -> copy (bitmap-skipped) -> cvtw (weights L2-hot) -> gru
        smu_clear_kernel<<<(bm_words + 255) / 256, 256, 0, stream>>>(bm, bm_words);
        smu_bits_kernel<<<(n_upd + 255) / 256, 256, 0, stream>>>(ids, bm, n_upd);
        smu_copy_skip_kernel<<<2048, 256, 0, stream>>>(mem, lu, bm, out_mem, out_lu, n_nodes);
        smu_cvtw_kernel<<<(W_TOT_ELEMS + 255) / 256, 256, 0, stream>>>(Wih, Whh, wsw);
        smu_gru_kernel<true><<<grid, NTHR, 0, stream>>>(
            ids, msg, ts, mem, Wih, Whh, bih, bhh, gam, bet, wsw, out_mem, out_lu);
    } else {
        // fallback: full copy first, then GRU scatter overwrites updated rows
        long n_mem4 = n_nodes * (MEMH / 4);
        long n_lu4  = n_nodes / 4;
        smu_copy_kernel<<<2048, 256, 0, stream>>>(mem, lu, out_mem, out_lu, n_mem4, n_lu4);
        if (ws_w) {
            smu_cvtw_kernel<<<(W_TOT_ELEMS + 255) / 256, 256, 0, stream>>>(Wih, Whh, wsw);
            smu_gru_kernel<true><<<grid, NTHR, 0, stream>>>(
                ids, msg, ts, mem, Wih, Whh, bih, bhh, gam, bet, wsw, out_mem, out_lu);
        } else {
            smu_gru_kernel<false><<<grid, NTHR, 0, stream>>>(
                ids, msg, ts, mem, Wih, Whh, bih, bhh, gam, bet, nullptr, out_mem, out_lu);
        }
    }
}